// Round 4
// baseline (829.578 us; speedup 1.0000x reference)
//
#include <hip/hip_runtime.h>
#include <math.h>

#define FIELD 2097152   // 32*512*128
#define NSEQ  4096      // 32*128 sequences

typedef float f2 __attribute__((ext_vector_type(2)));   // (re, im) -> VGPR pair

__device__ __forceinline__ f2 swp(f2 a) { return __builtin_shufflevector(a, a, 1, 0); }
__device__ __forceinline__ f2 conjf2(f2 a) { return (f2){a.x, -a.y}; }
// multiply by (c + i s), with ns = (-s, s): 1 pk_mul + 1 pk_fma (swap -> op_sel)
__device__ __forceinline__ f2 cmulp(f2 a, float c, f2 ns)  { return c * a + ns * swp(a); }
// multiply by (c - i s)
__device__ __forceinline__ f2 cmulpc(f2 a, float c, f2 ns) { return c * a - ns * swp(a); }
// a + i*b  /  a - i*b
__device__ __forceinline__ f2 addi(f2 a, f2 b) { return a + (f2){-1.0f, 1.0f} * swp(b); }
__device__ __forceinline__ f2 subi(f2 a, f2 b) { return a + (f2){1.0f, -1.0f} * swp(b); }

// ---- xor-lane exchange: DPP (VALU-speed) for h in {1,2,4,8}; bpermute-based
// ---- __shfl_xor only for cross-row h in {16,32}. DS pipe runs parallel to
// ---- VALU and is TLP-hidden (r1: moving these to VALU permlane regressed).
template<int CTRL>
__device__ __forceinline__ float dpp_f(float v) {
  return __int_as_float(__builtin_amdgcn_update_dpp(
      __float_as_int(v), __float_as_int(v), CTRL, 0xF, 0xF, true));
}
template<int CTRL>
__device__ __forceinline__ float dpp0_f(float v) {   // old=0, invalid lanes -> 0
  return __int_as_float(__builtin_amdgcn_update_dpp(
      0, __float_as_int(v), CTRL, 0xF, 0xF, true));
}
template<int H>
__device__ __forceinline__ float xlane(float v) {
  if constexpr (H == 1)      return dpp_f<0xB1>(v);    // quad_perm [1,0,3,2] = xor1
  else if constexpr (H == 2) return dpp_f<0x4E>(v);    // quad_perm [2,3,0,1] = xor2
  else if constexpr (H == 4) return dpp_f<0x141>(dpp_f<0x1B>(v)); // xor7 o xor3 = xor4
  else if constexpr (H == 8) return dpp_f<0x128>(v);   // row_ror:8 = xor8
  else return __shfl_xor(v, H, 64);
}
template<int H>
__device__ __forceinline__ f2 xlane2(f2 v) {
  return (f2){xlane<H>(v.x), xlane<H>(v.y)};
}
__device__ __forceinline__ f2 shfl2(f2 v, int l) {
  return (f2){__shfl(v.x, l, 64), __shfl(v.y, l, 64)};
}
__device__ __forceinline__ float bcast0(float v) {
  return __int_as_float(__builtin_amdgcn_readfirstlane(__float_as_int(v)));
}
// 64-lane sum, zero DS ops: row_shr prefix adds + row_bcast15/31.
__device__ __forceinline__ float wave_sum(float v) {
  v += dpp0_f<0x111>(v);   // row_shr:1
  v += dpp0_f<0x112>(v);   // row_shr:2
  v += dpp0_f<0x114>(v);   // row_shr:4
  v += dpp0_f<0x118>(v);   // row_shr:8
  v += dpp0_f<0x142>(v);   // row_bcast15
  v += dpp0_f<0x143>(v);   // row_bcast31 -> lane 63 holds total
  return __int_as_float(__builtin_amdgcn_readlane(__float_as_int(v), 63));
}

// Lane-dimension butterfly stages on a 2-register set (the per-wave half).
// Lane-masked twiddles: lo lanes hold W=(1,0). sg = +1 lo / -1 hi.
template<int H>
__device__ __forceinline__ void fwd_stage2(f2* v, float wr, f2 wn, float sg) {
#pragma unroll
  for (int b = 0; b < 2; ++b) {
    f2 p = xlane2<H>(v[b]);
    f2 t = sg * v[b] + p;          // lo: v+p ; hi: p-v
    v[b] = cmulp(t, wr, wn);       // lo: *1 ; hi: *e^{-i th}
  }
}
template<int H>
__device__ __forceinline__ void inv_stage2(f2* v, float wr, f2 wn, float sg) {
#pragma unroll
  for (int b = 0; b < 2; ++b) {
    f2 u = cmulpc(v[b], wr, wn);   // lo: v ; hi: v*e^{+i th} (conj W)
    f2 p = xlane2<H>(u);
    v[b] = sg * u + p;             // lo: u+p ; hi: p-u
  }
}
__device__ __forceinline__ void lanes_fwd(f2* v, const float* wrS, const f2* wnS,
                                          const float* sgS) {
  fwd_stage2<32>(v, wrS[0], wnS[0], sgS[0]);
  fwd_stage2<16>(v, wrS[1], wnS[1], sgS[1]);
  fwd_stage2<8> (v, wrS[2], wnS[2], sgS[2]);
  fwd_stage2<4> (v, wrS[3], wnS[3], sgS[3]);
  fwd_stage2<2> (v, wrS[4], wnS[4], sgS[4]);
  fwd_stage2<1> (v, wrS[5], wnS[5], sgS[5]);
}
__device__ __forceinline__ void lanes_inv(f2* v, const float* wrS, const f2* wnS,
                                          const float* sgS) {
  inv_stage2<1> (v, wrS[5], wnS[5], sgS[5]);
  inv_stage2<2> (v, wrS[4], wnS[4], sgS[4]);
  inv_stage2<4> (v, wrS[3], wnS[3], sgS[3]);
  inv_stage2<8> (v, wrS[2], wnS[2], sgS[2]);
  inv_stage2<16>(v, wrS[1], wnS[1], sgS[1]);
  inv_stage2<32>(v, wrS[0], wnS[0], sgS[0]);
}

// Half-spectrum (this wave's 2 bins b=2j+h) -> packed-Z regs for the split
// inverse. Partner bins (4-b)&3 are intra-wave for both parities.
__device__ __forceinline__ void halfz2(f2* S, float S256, int h, int lane,
                                       int pl0, int plx,
                                       const float* twHc, const f2* twHn) {
  f2 P[2];
  P[0] = shfl2(h ? S[1] : S[0], h ? plx : pl0);
  P[1] = shfl2(h ? S[0] : S[1], plx);
  if (h == 0 && lane == 0) P[0] = (f2){S256, 0.0f};
#pragma unroll
  for (int j = 0; j < 2; ++j) {
    f2 cP = conjf2(P[j]);
    f2 A = 0.5f * (S[j] + cP);
    f2 B = 0.5f * (S[j] - cP);
    f2 Bt = cmulp(B, twHc[j], twHn[j]);   // B * e^{+i th}
    S[j] = addi(A, Bt);
  }
}

// Per-bin mode update, bitwise-identical math to the verified r0 kernel.
__device__ __forceinline__ void mode2(const f2* X, const f2* V, f2* U,
                                      const float* l1, const float* l2,
                                      float om, const float* fb) {
#pragma unroll
  for (int j = 0; j < 2; ++j) {
    float f = fb[j];
    float dfp = f - om;
    float dfm = f + om;
    float gp = __builtin_amdgcn_rcpf(fmaf(1600.0f * dfp, dfp, 1.0f));
    float gm = __builtin_amdgcn_rcpf(fmaf(1600.0f * dfm, dfm, 1.0f));
    float gs = 0.5f * (gp + gm);
    f2 D = X[j] - V[j];
    float lt = 0.25f * fmaf(l1[j], gp, l2[j] * gm);
    U[j] = gs * D + (f2){lt, 0.0f};
  }
}

// r4: TWO waves per sequence (h=0: bins {4r,4r+2}/slots {0,1}/_256 scalars;
// h=1: bins {4r+1,4r+3}/slots {2,3}). 8192 waves = 32/CU = 8 waves/SIMD --
// double the TLP of the one-wave-per-seq design, attacking the ~29% idle
// issue slots (r3 showed op cuts don't move time => latency-bound).
// The 6 lane-FFT stages stay intra-wave on 2 regs; the slot radix-4 is
// intra-wave forward (reads from stage) and one LDS pair-exchange inverse.
// 2 barriers/iter (omega+exchange share one). Per-bin math identical to r0.
// NOTE (r2): lambda MUST stay time-domain (per-iter ifft required).
// NOTE (r1): keep cross-row exchanges on the DS pipe.
__global__ __attribute__((amdgpu_flat_work_group_size(512, 512),
                          amdgpu_waves_per_eu(8, 8)))
void vmd_kernel(const float* __restrict__ x, float* __restrict__ out,
                float* __restrict__ ws) {
  __shared__ float stage[4 * 512];    // [seq][n]: x staging -> per-iter exchange -> out packing
  __shared__ float ldsLam[4 * 512];   // psi-permuted lambda per seq; epilogue exchange
  __shared__ float4 omP4[4][2];       // omega partials per (seq, half)

  const int tid = threadIdx.x;
  const int wv = tid >> 6;
  const int lane = tid & 63;
  const int s = wv >> 1;              // seq within block
  const int h = wv & 1;               // half: bin parity
  const int w = (blockIdx.x >> 3) + ((blockIdx.x & 7) << 7);   // XCD swizzle
  const int g = 4 * w + s;
  const int bb = w >> 5;
  const int d0 = (4 * w) & 127;
  const int base4 = bb * 16384 + (d0 >> 2);
  float* lamS = ldsLam + s * 512;
  f2* stg2 = (f2*)stage + s * 256;    // packed (even,odd) pair view of this seq
  f2* exch = (f2*)ldsLam + s * 256;   // epilogue-only exchange region

  const int rev = (int)(__brev((unsigned)lane) >> 26);           // rev6(lane)
  const float f0 = (float)rev * (1.0f / 128.0f);
  const int plx = lane ^ 63;
  const int pl0 = (int)(__brev((unsigned)((64 - rev) & 63)) >> 26);
  const float sgh = h ? -1.0f : 1.0f;

  const int b0 = h, b1 = 2 + h;       // this wave's bins (j=0,1)
  float fb[2];
  fb[0] = f0 + (float)b0 * (1.0f / 512.0f);
  fb[1] = f0 + (float)b1 * (1.0f / 512.0f);

  // Stage twiddles, lane-masked: lo lanes = identity (wr=1, wn=0).
  float wrS[6], sgS[6]; f2 wnS[6];
#pragma unroll
  for (int st = 0; st < 6; ++st) {
    const int hh = 32 >> st;
    const bool hi = (lane & hh) != 0;
    float th = (float)(lane & (hh - 1)) * (3.14159265358979323846f / (float)hh);
    float sn, cs; sincosf(th, &sn, &cs);
    wrS[st] = hi ? cs : 1.0f;                       // W = e^{-i th}
    wnS[st] = hi ? (f2){sn, -sn} : (f2){0.0f, 0.0f};
    sgS[st] = hi ? -1.0f : 1.0f;
  }
  // Slot-radix twiddle (post-fft4 fwd / pre-fft4 inv): th = lane*b*2pi/256.
  // b=0 gives exact identity (c=1, ns=+-0) -> applied uniformly, harmless.
  float twFc2[2]; f2 twFn2[2];
#pragma unroll
  for (int j = 0; j < 2; ++j) {
    float th = (float)(lane * (2 * j + h)) * 0.02454369260617026f;
    float sn, cs; sincosf(th, &sn, &cs);
    twFc2[j] = cs; twFn2[j] = (f2){sn, -sn};
  }
  // Hermitian pack/unpack twiddle: th = (4rev+b)*2pi/512, e^{+i th}.
  float twHc2[2]; f2 twHn2[2];
#pragma unroll
  for (int j = 0; j < 2; ++j) {
    float th = (float)(4 * rev + 2 * j + h) * 0.01227184630308513f;
    float sn, cs; sincosf(th, &sn, &cs);
    twHc2[j] = cs; twHn2[j] = (f2){-sn, sn};
  }

  // ---- load x: float4 (n, d0..d0+3) -> stage[seq][n]; zero lambda ----
  {
    const float4* x4 = (const float4*)x;
    float4 va = x4[base4 + tid * 32];
    stage[tid]        = va.x; stage[512 + tid]  = va.y;
    stage[1024 + tid] = va.z; stage[1536 + tid] = va.w;
    ((float4*)ldsLam)[tid] = (float4){0.0f, 0.0f, 0.0f, 0.0f};
  }
  __syncthreads();

  // ---- forward FFT, split: slot radix-4 from LDS (no exchange), then
  // ---- 6 intra-wave lane stages on this wave's 2 regs ----
  f2 z[2], xa[2];
  {
    f2 s0 = stg2[lane], s1 = stg2[64 + lane], s2 = stg2[128 + lane], s3 = stg2[192 + lane];
    xa[0] = h ? s2 : s0;              // own time slots 2h, 2h+1
    xa[1] = h ? s3 : s1;
    if (h == 0) {
      f2 e0 = s0 + s2, e1 = s1 + s3;  // t0, t2
      z[0] = e0 + e1;                 // v0 (b=0)
      z[1] = e0 - e1;                 // v2 (b=2)
    } else {
      f2 o0 = s0 - s2, o1 = s1 - s3;  // t1, t3
      z[0] = subi(o0, o1);            // v1 (b=1)
      z[1] = addi(o0, o1);            // v3 (b=3)
    }
    z[0] = cmulp(z[0], twFc2[0], twFn2[0]);
    z[1] = cmulp(z[1], twFc2[1], twFn2[1]);
    lanes_fwd(z, wrS, wnS, sgS);
  }
  __syncthreads();   // stage becomes the per-iter exchange buffer below

  // ---- Hermitian unpack -> X (this wave's 2 bins), X256 on h=0 ----
  f2 X[2];
  float X256;
  {
    f2 P[2];
    P[0] = shfl2(h ? z[1] : z[0], h ? plx : pl0);
    P[1] = shfl2(h ? z[0] : z[1], plx);
    X256 = bcast0(z[0].x - z[0].y);   // meaningful on h=0 only
#pragma unroll
    for (int j = 0; j < 2; ++j) {
      f2 cP = conjf2(P[j]);
      f2 E = 0.5f * (z[j] + cP);
      f2 O = 0.5f * (f2){1.0f, -1.0f} * swp(z[j] - cP);   // -i*(z-cP)/2
      X[j] = E + cmulpc(O, twHc2[j], twHn2[j]);           // O * e^{-i th}
    }
  }

  f2 U0[2], U1[2], lam[2];
#pragma unroll
  for (int j = 0; j < 2; ++j) {
    U0[j] = (f2){0.0f, 0.0f}; U1[j] = (f2){0.0f, 0.0f}; lam[j] = (f2){0.0f, 0.0f};
  }
  float U0_256 = 0.0f, U1_256 = 0.0f;
  float om0 = 0.0f, om1 = 0.0f;

  // Loop-invariant lambda addresses (psi-permuted layout, same as r0).
  const int psiW = 256 * (lane & 1) + (lane >> 1) + 64 * h;  // write base (slots 2h+j)
  const int a1_0 = 128 * b0 + 64 + rev;
  const int a1_1 = 128 * b1 + 64 + rev;
  const int a2_0 = (b0 == 0) ? (64 - rev) : (128 * (4 - b0) + 63 - rev);
  const int a2_1 = 128 * (4 - b1) + 63 - rev;

#pragma unroll 1
  for (int it = 0; it < 50; ++it) {
    float l1[2], l2[2];
    l1[0] = lamS[a1_0]; l1[1] = lamS[a1_1];
    l2[0] = lamS[a2_0]; l2[1] = lamS[a2_1];
    float lam0 = lamS[0];

    mode2(X, U1, U0, l1, l2, om0, fb);
    if (h == 0) {
      float dm = 0.5f + om0;
      float gg = __builtin_amdgcn_rcpf(fmaf(1600.0f * dm, dm, 1.0f));
      U0_256 = (X256 - U1_256 + 0.5f * lam0) * gg;
    }
    mode2(X, U0, U1, l1, l2, om1, fb);
    if (h == 0) {
      float dm = 0.5f + om1;
      float gg = __builtin_amdgcn_rcpf(fmaf(1600.0f * dm, dm, 1.0f));
      U1_256 = (X256 - U0_256 + 0.5f * lam0) * gg;
    }

    // omega partials over this wave's 2 bins, wave-reduced (pure DPP)
    float n0 = 0.0f, d0s = 0.0f, n1 = 0.0f, d1s = 0.0f;
#pragma unroll
    for (int j = 0; j < 2; ++j) {
      float f = fb[j];
      float p0 = fmaf(U0[j].x, U0[j].x, U0[j].y * U0[j].y);
      float p1 = fmaf(U1[j].x, U1[j].x, U1[j].y * U1[j].y);
      d0s += p0; n0 = fmaf(f, p0, n0);
      d1s += p1; n1 = fmaf(f, p1, n1);
    }
    n0 = wave_sum(n0); d0s = wave_sum(d0s);
    n1 = wave_sum(n1); d1s = wave_sum(d1s);

    const bool more = it < 49;
    f2 tA, tB;
    if (more) {   // split inverse FFT of S = U0+U1 up to the slot radix-4
      f2 zz[2];
      zz[0] = U0[0] + U1[0];
      zz[1] = U0[1] + U1[1];
      float S256 = U0_256 + U1_256;
      halfz2(zz, S256, h, lane, pl0, plx, twHc2, twHn2);
      lanes_inv(zz, wrS, wnS, sgS);
      zz[0] = cmulpc(zz[0], twFc2[0], twFn2[0]);
      zz[1] = cmulpc(zz[1], twFc2[1], twFn2[1]);
      tA = zz[0] + zz[1];   // h=0: t0 = v0+v2 ; h=1: t2 = v1+v3
      tB = zz[0] - zz[1];   // h=0: t1        ; h=1: t3
      stg2[h * 128 + lane]      = tA;
      stg2[h * 128 + 64 + lane] = tB;
    }
    if (lane == 0) omP4[s][h] = (float4){n0, d0s, n1, d1s};
    __syncthreads();   // omega partials + exchange halves visible
    {
      float4 pp = omP4[s][1 - h];
      om0 = (n0 + pp.x) * __builtin_amdgcn_rcpf((d0s + pp.y) + 1e-7f);
      om1 = (n1 + pp.z) * __builtin_amdgcn_rcpf((d1s + pp.w) + 1e-7f);
    }
    if (more) {
      f2 pA = stg2[(1 - h) * 128 + lane];
      f2 pB = stg2[(1 - h) * 128 + 64 + lane];
      f2 oA = pA + sgh * tA;                       // h0: t0+t2 ; h1: t0-t2
      f2 u  = h ? pB : tB;
      f2 vv = h ? tB : pB;
      f2 oB = u + sgh * (f2){-1.0f, 1.0f} * swp(vv);  // h0: t1+i*t3 ; h1: t3' = t1-i*t3
      lam[0] = lam[0] + 0.001f * (xa[0] - oA * (1.0f / 256.0f));
      lam[1] = lam[1] + 0.001f * (xa[1] - oB * (1.0f / 256.0f));
      lamS[psiW]            = lam[0].x;
      lamS[psiW + 128]      = lam[0].y;
      lamS[psiW + 32]       = lam[1].x;
      lamS[psiW + 32 + 128] = lam[1].y;
      __syncthreads();   // lambda visible cross-wave; exchange buffer reusable
    }
  }

  // ---- final modes: split ifft per mode, pack to stage, float4 stores ----
  // (epilogue exchange via ldsLam -- lambda is dead after the loop)
  float4* o4 = (float4*)out;
#pragma unroll 1
  for (int m = 0; m < 2; ++m) {
    f2 zz[2];
    zz[0] = m ? U1[0] : U0[0];
    zz[1] = m ? U1[1] : U0[1];
    float S256 = m ? U1_256 : U0_256;
    halfz2(zz, S256, h, lane, pl0, plx, twHc2, twHn2);
    lanes_inv(zz, wrS, wnS, sgS);
    zz[0] = cmulpc(zz[0], twFc2[0], twFn2[0]);
    zz[1] = cmulpc(zz[1], twFc2[1], twFn2[1]);
    f2 tA = zz[0] + zz[1], tB = zz[0] - zz[1];
    exch[h * 128 + lane]      = tA;
    exch[h * 128 + 64 + lane] = tB;
    __syncthreads();
    f2 pA = exch[(1 - h) * 128 + lane];
    f2 pB = exch[(1 - h) * 128 + 64 + lane];
    f2 oA = pA + sgh * tA;
    f2 u  = h ? pB : tB;
    f2 vv = h ? tB : pB;
    f2 oB = u + sgh * (f2){-1.0f, 1.0f} * swp(vv);
    stg2[64 * (2 * h + 0) + lane] = oA * (1.0f / 256.0f);
    stg2[64 * (2 * h + 1) + lane] = oB * (1.0f / 256.0f);
    __syncthreads();
    float4 v;
    v.x = stage[tid]; v.y = stage[512 + tid];
    v.z = stage[1024 + tid]; v.w = stage[1536 + tid];
    o4[(m + 1) * (FIELD / 4) + base4 + tid * 32] = v;
    __syncthreads();   // stage reuse barrier for the next mode
  }

  if (lane == 0 && h == 0) {
    ws[g] = om0;             // omega staging in workspace (read-only for epi)
    ws[NSEQ + g] = om1;
  }
}

// Fused epilogue: per-batch flag recomputed per block (64 ws reads + wave
// reduce), trend slice zeroed, period/res conditionally swapped.
__global__ __launch_bounds__(256) void epi_kernel(float* __restrict__ out,
                                                  const float* __restrict__ ws) {
  const int tid = threadIdx.x;
  const int blk = blockIdx.x;          // 0..2047; 64 blocks per batch
  const int bb = blk >> 6;
  __shared__ float flagS;
  if (tid < 64) {
    float o0 = ws[bb * 128 + tid] + ws[bb * 128 + 64 + tid];
    float o1 = ws[NSEQ + bb * 128 + tid] + ws[NSEQ + bb * 128 + 64 + tid];
#pragma unroll
    for (int off = 32; off >= 1; off >>= 1) {
      o0 += __shfl_xor(o0, off, 64);
      o1 += __shfl_xor(o1, off, 64);
    }
    if (tid == 0) flagS = (o0 > o1) ? 1.0f : 0.0f;   // swap iff mean0 > mean1
  }
  __syncthreads();
  const bool sw = flagS > 0.5f;
  float4* o4 = (float4*)out;
  const int i = blk * 256 + tid;       // float4 index within trend field
  o4[i] = (float4){0.0f, 0.0f, 0.0f, 0.0f};
  if (sw) {
    float4 p = o4[FIELD / 4 + i];
    float4 r = o4[2 * FIELD / 4 + i];
    o4[FIELD / 4 + i] = r;
    o4[2 * FIELD / 4 + i] = p;
  }
}

extern "C" void kernel_launch(void* const* d_in, const int* in_sizes, int n_in,
                              void* d_out, int out_size, void* d_ws, size_t ws_size,
                              hipStream_t stream) {
  (void)in_sizes; (void)n_in; (void)ws_size; (void)out_size;
  const float* x = (const float*)d_in[0];
  float* out = (float*)d_out;
  float* ws = (float*)d_ws;
  vmd_kernel<<<NSEQ / 4, 512, 0, stream>>>(x, out, ws);
  epi_kernel<<<FIELD / 1024, 256, 0, stream>>>(out, ws);
}

// Round 5
// 344.379 us; speedup vs baseline: 2.4089x; 2.4089x over previous
//
#include <hip/hip_runtime.h>
#include <math.h>

#define FIELD 2097152   // 32*512*128
#define NSEQ  4096      // 32*128 sequences

typedef float f2 __attribute__((ext_vector_type(2)));   // (re, im) -> VGPR pair

__device__ __forceinline__ f2 swp(f2 a) { return __builtin_shufflevector(a, a, 1, 0); }
__device__ __forceinline__ f2 conjf2(f2 a) { return (f2){a.x, -a.y}; }
// multiply by (c + i s), with ns = (-s, s): 1 pk_mul + 1 pk_fma (swap -> op_sel)
__device__ __forceinline__ f2 cmulp(f2 a, float c, f2 ns)  { return c * a + ns * swp(a); }
// multiply by (c - i s)
__device__ __forceinline__ f2 cmulpc(f2 a, float c, f2 ns) { return c * a - ns * swp(a); }
// a + i*b  /  a - i*b
__device__ __forceinline__ f2 addi(f2 a, f2 b) { return a + (f2){-1.0f, 1.0f} * swp(b); }
__device__ __forceinline__ f2 subi(f2 a, f2 b) { return a + (f2){1.0f, -1.0f} * swp(b); }

// ---- xor-lane exchange: DPP (VALU-speed) for h in {1,2,4,8}; bpermute-based
// ---- __shfl_xor only for cross-row h in {16,32}. DS pipe runs parallel to
// ---- VALU and is TLP-hidden (r1: moving these to VALU permlane regressed).
template<int CTRL>
__device__ __forceinline__ float dpp_f(float v) {
  return __int_as_float(__builtin_amdgcn_update_dpp(
      __float_as_int(v), __float_as_int(v), CTRL, 0xF, 0xF, true));
}
template<int CTRL>
__device__ __forceinline__ float dpp0_f(float v) {   // old=0, invalid lanes -> 0
  return __int_as_float(__builtin_amdgcn_update_dpp(
      0, __float_as_int(v), CTRL, 0xF, 0xF, true));
}
template<int H>
__device__ __forceinline__ float xlane(float v) {
  if constexpr (H == 1)      return dpp_f<0xB1>(v);    // quad_perm [1,0,3,2] = xor1
  else if constexpr (H == 2) return dpp_f<0x4E>(v);    // quad_perm [2,3,0,1] = xor2
  else if constexpr (H == 4) return dpp_f<0x141>(dpp_f<0x1B>(v)); // xor7 o xor3 = xor4
  else if constexpr (H == 8) return dpp_f<0x128>(v);   // row_ror:8 = xor8
  else return __shfl_xor(v, H, 64);
}
template<int H>
__device__ __forceinline__ f2 xlane2(f2 v) {
  return (f2){xlane<H>(v.x), xlane<H>(v.y)};
}
__device__ __forceinline__ f2 shfl2(f2 v, int l) {
  return (f2){__shfl(v.x, l, 64), __shfl(v.y, l, 64)};
}
__device__ __forceinline__ float bcast0(float v) {
  return __int_as_float(__builtin_amdgcn_readfirstlane(__float_as_int(v)));
}
// 64-lane sum, zero DS ops: row_shr prefix adds + row_bcast15/31.
__device__ __forceinline__ float wave_sum(float v) {
  v += dpp0_f<0x111>(v);   // row_shr:1
  v += dpp0_f<0x112>(v);   // row_shr:2
  v += dpp0_f<0x114>(v);   // row_shr:4
  v += dpp0_f<0x118>(v);   // row_shr:8
  v += dpp0_f<0x142>(v);   // row_bcast15
  v += dpp0_f<0x143>(v);   // row_bcast31 -> lane 63 holds total
  return __int_as_float(__builtin_amdgcn_readlane(__float_as_int(v), 63));
}

// Lane-dimension butterfly stages on the per-wave 2-register set, twiddle
// record from LDS: float4 (wr, wn.x, wn.y, sg). Lane-masked: lo lanes hold
// (1, 0,0, +1), hi lanes (cos, sin,-sin, -1).
template<int H>
__device__ __forceinline__ void fwd_q(f2* v, float4 t) {
  const float wr = t.x; const f2 wn = (f2){t.y, t.z}; const float sg = t.w;
#pragma unroll
  for (int b = 0; b < 2; ++b) {
    f2 p = xlane2<H>(v[b]);
    f2 tt = sg * v[b] + p;         // lo: v+p ; hi: p-v
    v[b] = cmulp(tt, wr, wn);      // lo: *1 ; hi: *e^{-i th}
  }
}
template<int H>
__device__ __forceinline__ void inv_q(f2* v, float4 t) {
  const float wr = t.x; const f2 wn = (f2){t.y, t.z}; const float sg = t.w;
#pragma unroll
  for (int b = 0; b < 2; ++b) {
    f2 u = cmulpc(v[b], wr, wn);   // lo: v ; hi: v*e^{+i th} (conj W)
    f2 p = xlane2<H>(u);
    v[b] = sg * u + p;             // lo: u+p ; hi: p-u
  }
}

// Half-spectrum (this wave's 2 bins b=2j+h) -> packed-Z regs for the split
// inverse. Partner bins (4-b)&3 are intra-wave for both parities.
__device__ __forceinline__ void halfz2(f2* S, float S256, int h, int lane,
                                       int pl0, int plx,
                                       const float* twHc, const f2* twHn) {
  f2 P[2];
  P[0] = shfl2(h ? S[1] : S[0], h ? plx : pl0);
  P[1] = shfl2(h ? S[0] : S[1], plx);
  if (h == 0 && lane == 0) P[0] = (f2){S256, 0.0f};
#pragma unroll
  for (int j = 0; j < 2; ++j) {
    f2 cP = conjf2(P[j]);
    f2 A = 0.5f * (S[j] + cP);
    f2 B = 0.5f * (S[j] - cP);
    f2 Bt = cmulp(B, twHc[j], twHn[j]);   // B * e^{+i th}
    S[j] = addi(A, Bt);
  }
}

// Per-bin mode update, bitwise-identical math to the verified r0 kernel.
__device__ __forceinline__ void mode2(const f2* X, const f2* V, f2* U,
                                      const float* l1, const float* l2,
                                      float om, const float* fb) {
#pragma unroll
  for (int j = 0; j < 2; ++j) {
    float f = fb[j];
    float dfp = f - om;
    float dfm = f + om;
    float gp = __builtin_amdgcn_rcpf(fmaf(1600.0f * dfp, dfp, 1.0f));
    float gm = __builtin_amdgcn_rcpf(fmaf(1600.0f * dfm, dfm, 1.0f));
    float gs = 0.5f * (gp + gm);
    f2 D = X[j] - V[j];
    float lt = 0.25f * fmaf(l1[j], gp, l2[j] * gm);
    U[j] = gs * D + (f2){lt, 0.0f};
  }
}

// r5 = r4's verified 2-waves-per-sequence split (8192 waves = 8/SIMD) with
// the REGISTER DIET that r4 lacked: all loop-invariant twiddles (stage
// wr/wn/sg, slot twF, Hermitian twH) live in block-shared LDS (computed
// once per block), x is re-read from stage (exchange moved to exchB), so
// live VGPRs stay under the 64-reg / 8-wave budget. r4 spilled (VGPR 32,
// FETCH 2.5 GB scratch, 780 us); concept untested until now.
// NOTE (r3): op cuts alone don't move time -- latency-bound at 4 waves.
// NOTE (r2): lambda MUST stay time-domain (per-iter ifft required).
// NOTE (r1): keep cross-row exchanges on the DS pipe.
__global__ __attribute__((amdgpu_flat_work_group_size(512, 512),
                          amdgpu_waves_per_eu(8)))
void vmd_kernel(const float* __restrict__ x, float* __restrict__ out,
                float* __restrict__ ws) {
  __shared__ float stage[4 * 512];    // [seq][n]: x resident all loop; out packing in epilogue
  __shared__ float ldsLam[4 * 512];   // psi-permuted lambda per seq
  __shared__ float exchB[4 * 512];    // per-iter + epilogue slot-radix exchange
  __shared__ float4 twS[6 * 64];      // stage twiddles (wr, wn.x, wn.y, sg) per (stage, lane)
  __shared__ float twFH[2 * 64 * 16]; // per (h, lane): [0..5]=H (c,nx,ny)x2, [6..11]=F, pad to 64B
  __shared__ float4 omP4[4][2];       // omega partials per (seq, half)

  const int tid = threadIdx.x;
  const int wv = tid >> 6;
  const int lane = tid & 63;
  const int s = wv >> 1;              // seq within block
  const int h = wv & 1;               // half: bin parity
  const int w = (blockIdx.x >> 3) + ((blockIdx.x & 7) << 7);   // XCD swizzle
  const int g = 4 * w + s;
  const int bb = w >> 5;
  const int d0 = (4 * w) & 127;
  const int base4 = bb * 16384 + (d0 >> 2);
  float* lamS = ldsLam + s * 512;
  f2* stg2 = (f2*)stage + s * 256;    // packed (even,odd) pair view of this seq
  f2* exch2 = (f2*)exchB + s * 256;

  const int rev = (int)(__brev((unsigned)lane) >> 26);           // rev6(lane)
  const float f0 = (float)rev * (1.0f / 128.0f);
  const int plx = lane ^ 63;
  const int pl0 = (int)(__brev((unsigned)((64 - rev) & 63)) >> 26);
  const float sgh = h ? -1.0f : 1.0f;

  const int b0 = h, b1 = 2 + h;       // this wave's bins (j=0,1)
  float fb[2];
  fb[0] = f0 + (float)b0 * (1.0f / 512.0f);
  fb[1] = f0 + (float)b1 * (1.0f / 512.0f);

  // ---- block-shared twiddle fill (once; waves split the sincos work) ----
  if (wv < 6) {
    const int hh = 32 >> wv;
    const bool hi = (lane & hh) != 0;
    float th = (float)(lane & (hh - 1)) * (3.14159265358979323846f / (float)hh);
    float sn, cs; sincosf(th, &sn, &cs);
    twS[wv * 64 + lane] = hi ? (float4){cs, sn, -sn, -1.0f}
                             : (float4){1.0f, 0.0f, 0.0f, 1.0f};
  } else if (wv == 6) {               // F: slot-radix twiddle, e^{-i th}
#pragma unroll
    for (int hp = 0; hp < 2; ++hp)
#pragma unroll
      for (int j = 0; j < 2; ++j) {
        float th = (float)(lane * (2 * j + hp)) * 0.02454369260617026f;  // 2pi/256
        float sn, cs; sincosf(th, &sn, &cs);
        const int base = (hp * 64 + lane) * 16 + 6 + j * 3;
        twFH[base] = cs; twFH[base + 1] = sn; twFH[base + 2] = -sn;
      }
  } else {                            // H: Hermitian twiddle, e^{+i th}
#pragma unroll
    for (int hp = 0; hp < 2; ++hp)
#pragma unroll
      for (int j = 0; j < 2; ++j) {
        float th = (float)(4 * rev + 2 * j + hp) * 0.01227184630308513f; // 2pi/512
        float sn, cs; sincosf(th, &sn, &cs);
        const int base = (hp * 64 + lane) * 16 + j * 3;
        twFH[base] = cs; twFH[base + 1] = -sn; twFH[base + 2] = sn;
      }
  }

  // ---- load x: float4 (n, d0..d0+3) -> stage[seq][n]; zero lambda ----
  {
    const float4* x4 = (const float4*)x;
    float4 va = x4[base4 + tid * 32];
    stage[tid]        = va.x; stage[512 + tid]  = va.y;
    stage[1024 + tid] = va.z; stage[1536 + tid] = va.w;
    ((float4*)ldsLam)[tid] = (float4){0.0f, 0.0f, 0.0f, 0.0f};
  }
  __syncthreads();

  const float4* twSl = twS + lane;
  const float4* twR = (const float4*)(twFH + (h * 64 + lane) * 16);

  // ---- forward FFT, split: slot radix-4 from LDS (no exchange), then
  // ---- 6 intra-wave lane stages; twiddles streamed from LDS ----
  f2 z[2];
  {
    f2 s0 = stg2[lane], s1 = stg2[64 + lane], s2 = stg2[128 + lane], s3 = stg2[192 + lane];
    if (h == 0) {
      f2 e0 = s0 + s2, e1 = s1 + s3;  // t0, t2
      z[0] = e0 + e1;                 // v0 (b=0)
      z[1] = e0 - e1;                 // v2 (b=2)
    } else {
      f2 o0 = s0 - s2, o1 = s1 - s3;  // t1, t3
      z[0] = subi(o0, o1);            // v1 (b=1)
      z[1] = addi(o0, o1);            // v3 (b=3)
    }
    float4 q0 = twR[0], q1 = twR[1], q2 = twR[2];
    float tFc[2]; f2 tFn[2];
    tFc[0] = q1.z; tFn[0] = (f2){q1.w, q2.x};
    tFc[1] = q2.y; tFn[1] = (f2){q2.z, q2.w};
    z[0] = cmulp(z[0], tFc[0], tFn[0]);
    z[1] = cmulp(z[1], tFc[1], tFn[1]);
    float4 ta = twSl[0], tb = twSl[64];
    fwd_q<32>(z, ta); ta = twSl[2 * 64];
    fwd_q<16>(z, tb); tb = twSl[3 * 64];
    fwd_q<8>(z, ta);  ta = twSl[4 * 64];
    fwd_q<4>(z, tb);  tb = twSl[5 * 64];
    fwd_q<2>(z, ta);
    fwd_q<1>(z, tb);
  }

  // ---- Hermitian unpack -> X (this wave's 2 bins), X256 on h=0 ----
  f2 X[2];
  float X256;
  {
    float4 q0 = twR[0], q1 = twR[1];
    float tHc[2]; f2 tHn[2];
    tHc[0] = q0.x; tHn[0] = (f2){q0.y, q0.z};
    tHc[1] = q0.w; tHn[1] = (f2){q1.x, q1.y};
    f2 P[2];
    P[0] = shfl2(h ? z[1] : z[0], h ? plx : pl0);
    P[1] = shfl2(h ? z[0] : z[1], plx);
    X256 = bcast0(z[0].x - z[0].y);   // meaningful on h=0 only
#pragma unroll
    for (int j = 0; j < 2; ++j) {
      f2 cP = conjf2(P[j]);
      f2 E = 0.5f * (z[j] + cP);
      f2 O = 0.5f * (f2){1.0f, -1.0f} * swp(z[j] - cP);   // -i*(z-cP)/2
      X[j] = E + cmulpc(O, tHc[j], tHn[j]);               // O * e^{-i th}
    }
  }

  f2 U0[2], U1[2], lam[2];
#pragma unroll
  for (int j = 0; j < 2; ++j) {
    U0[j] = (f2){0.0f, 0.0f}; U1[j] = (f2){0.0f, 0.0f}; lam[j] = (f2){0.0f, 0.0f};
  }
  float U0_256 = 0.0f, U1_256 = 0.0f;
  float om0 = 0.0f, om1 = 0.0f;

  // Loop-invariant lambda addresses (psi-permuted layout, same as r0/r4).
  const int psiW = 256 * (lane & 1) + (lane >> 1) + 64 * h;  // write base (slots 2h+j)
  const int a1_0 = 128 * b0 + 64 + rev;
  const int a1_1 = 128 * b1 + 64 + rev;
  const int a2_0 = (b0 == 0) ? (64 - rev) : (128 * (4 - b0) + 63 - rev);
  const int a2_1 = 128 * (4 - b1) + 63 - rev;

#pragma unroll 1
  for (int it = 0; it < 50; ++it) {
    // batched iter-start LDS loads: lambda, x slots, twiddle records
    float l1[2], l2[2];
    l1[0] = lamS[a1_0]; l1[1] = lamS[a1_1];
    l2[0] = lamS[a2_0]; l2[1] = lamS[a2_1];
    float lam0 = lamS[0];
    f2 xa0 = stg2[h * 128 + lane];          // x slot 2h
    f2 xa1 = stg2[h * 128 + 64 + lane];     // x slot 2h+1
    float4 q0 = twR[0], q1 = twR[1], q2 = twR[2];
    float tHc[2]; f2 tHn[2]; float tFc[2]; f2 tFn[2];
    tHc[0] = q0.x; tHn[0] = (f2){q0.y, q0.z};
    tHc[1] = q0.w; tHn[1] = (f2){q1.x, q1.y};
    tFc[0] = q1.z; tFn[0] = (f2){q1.w, q2.x};
    tFc[1] = q2.y; tFn[1] = (f2){q2.z, q2.w};

    mode2(X, U1, U0, l1, l2, om0, fb);
    if (h == 0) {
      float dm = 0.5f + om0;
      float gg = __builtin_amdgcn_rcpf(fmaf(1600.0f * dm, dm, 1.0f));
      U0_256 = (X256 - U1_256 + 0.5f * lam0) * gg;
    }
    mode2(X, U0, U1, l1, l2, om1, fb);
    if (h == 0) {
      float dm = 0.5f + om1;
      float gg = __builtin_amdgcn_rcpf(fmaf(1600.0f * dm, dm, 1.0f));
      U1_256 = (X256 - U0_256 + 0.5f * lam0) * gg;
    }

    // omega partials over this wave's 2 bins, wave-reduced (pure DPP)
    float n0 = 0.0f, d0s = 0.0f, n1 = 0.0f, d1s = 0.0f;
#pragma unroll
    for (int j = 0; j < 2; ++j) {
      float f = fb[j];
      float p0 = fmaf(U0[j].x, U0[j].x, U0[j].y * U0[j].y);
      float p1 = fmaf(U1[j].x, U1[j].x, U1[j].y * U1[j].y);
      d0s += p0; n0 = fmaf(f, p0, n0);
      d1s += p1; n1 = fmaf(f, p1, n1);
    }
    n0 = wave_sum(n0); d0s = wave_sum(d0s);
    n1 = wave_sum(n1); d1s = wave_sum(d1s);

    const bool more = it < 49;
    f2 tA, tB;
    if (more) {   // split inverse FFT of S = U0+U1 up to the slot radix-4
      f2 zz[2];
      zz[0] = U0[0] + U1[0];
      zz[1] = U0[1] + U1[1];
      float S256 = U0_256 + U1_256;
      halfz2(zz, S256, h, lane, pl0, plx, tHc, tHn);
      float4 ta = twSl[5 * 64], tb = twSl[4 * 64];
      inv_q<1>(zz, ta);  ta = twSl[3 * 64];
      inv_q<2>(zz, tb);  tb = twSl[2 * 64];
      inv_q<4>(zz, ta);  ta = twSl[1 * 64];
      inv_q<8>(zz, tb);  tb = twSl[0 * 64];
      inv_q<16>(zz, ta);
      inv_q<32>(zz, tb);
      zz[0] = cmulpc(zz[0], tFc[0], tFn[0]);
      zz[1] = cmulpc(zz[1], tFc[1], tFn[1]);
      tA = zz[0] + zz[1];   // h=0: t0 = v0+v2 ; h=1: t2 = v1+v3
      tB = zz[0] - zz[1];   // h=0: t1        ; h=1: t3
      exch2[h * 128 + lane]      = tA;
      exch2[h * 128 + 64 + lane] = tB;
    }
    if (lane == 0) omP4[s][h] = (float4){n0, d0s, n1, d1s};
    __syncthreads();   // omega partials + exchange halves visible
    {
      float4 pp = omP4[s][1 - h];
      om0 = (n0 + pp.x) * __builtin_amdgcn_rcpf((d0s + pp.y) + 1e-7f);
      om1 = (n1 + pp.z) * __builtin_amdgcn_rcpf((d1s + pp.w) + 1e-7f);
    }
    if (more) {
      f2 pA = exch2[(1 - h) * 128 + lane];
      f2 pB = exch2[(1 - h) * 128 + 64 + lane];
      f2 oA = pA + sgh * tA;                       // h0: t0+t2 ; h1: t0-t2
      f2 u  = h ? pB : tB;
      f2 vv = h ? tB : pB;
      f2 oB = u + sgh * (f2){-1.0f, 1.0f} * swp(vv);  // h0: t1+i*t3 ; h1: t1-i*t3
      lam[0] = lam[0] + 0.001f * (xa0 - oA * (1.0f / 256.0f));
      lam[1] = lam[1] + 0.001f * (xa1 - oB * (1.0f / 256.0f));
      lamS[psiW]            = lam[0].x;
      lamS[psiW + 128]      = lam[0].y;
      lamS[psiW + 32]       = lam[1].x;
      lamS[psiW + 32 + 128] = lam[1].y;
      __syncthreads();   // lambda visible cross-wave; exchange buffer reusable
    }
  }

  // ---- final modes: split ifft per mode, pack to stage, float4 stores ----
  float4* o4 = (float4*)out;
#pragma unroll 1
  for (int m = 0; m < 2; ++m) {
    float4 q0 = twR[0], q1 = twR[1], q2 = twR[2];
    float tHc[2]; f2 tHn[2]; float tFc[2]; f2 tFn[2];
    tHc[0] = q0.x; tHn[0] = (f2){q0.y, q0.z};
    tHc[1] = q0.w; tHn[1] = (f2){q1.x, q1.y};
    tFc[0] = q1.z; tFn[0] = (f2){q1.w, q2.x};
    tFc[1] = q2.y; tFn[1] = (f2){q2.z, q2.w};
    f2 zz[2];
    zz[0] = m ? U1[0] : U0[0];
    zz[1] = m ? U1[1] : U0[1];
    float S256 = m ? U1_256 : U0_256;
    halfz2(zz, S256, h, lane, pl0, plx, tHc, tHn);
    float4 ta = twSl[5 * 64], tb = twSl[4 * 64];
    inv_q<1>(zz, ta);  ta = twSl[3 * 64];
    inv_q<2>(zz, tb);  tb = twSl[2 * 64];
    inv_q<4>(zz, ta);  ta = twSl[1 * 64];
    inv_q<8>(zz, tb);  tb = twSl[0 * 64];
    inv_q<16>(zz, ta);
    inv_q<32>(zz, tb);
    zz[0] = cmulpc(zz[0], tFc[0], tFn[0]);
    zz[1] = cmulpc(zz[1], tFc[1], tFn[1]);
    f2 tA = zz[0] + zz[1], tB = zz[0] - zz[1];
    exch2[h * 128 + lane]      = tA;
    exch2[h * 128 + 64 + lane] = tB;
    __syncthreads();
    f2 pA = exch2[(1 - h) * 128 + lane];
    f2 pB = exch2[(1 - h) * 128 + 64 + lane];
    f2 oA = pA + sgh * tA;
    f2 u  = h ? pB : tB;
    f2 vv = h ? tB : pB;
    f2 oB = u + sgh * (f2){-1.0f, 1.0f} * swp(vv);
    stg2[64 * (2 * h + 0) + lane] = oA * (1.0f / 256.0f);
    stg2[64 * (2 * h + 1) + lane] = oB * (1.0f / 256.0f);
    __syncthreads();
    float4 v;
    v.x = stage[tid]; v.y = stage[512 + tid];
    v.z = stage[1024 + tid]; v.w = stage[1536 + tid];
    o4[(m + 1) * (FIELD / 4) + base4 + tid * 32] = v;
    __syncthreads();   // stage reuse barrier for the next mode
  }

  if (lane == 0 && h == 0) {
    ws[g] = om0;             // omega staging in workspace (read-only for epi)
    ws[NSEQ + g] = om1;
  }
}

// Fused epilogue: per-batch flag recomputed per block (64 ws reads + wave
// reduce), trend slice zeroed, period/res conditionally swapped.
__global__ __launch_bounds__(256) void epi_kernel(float* __restrict__ out,
                                                  const float* __restrict__ ws) {
  const int tid = threadIdx.x;
  const int blk = blockIdx.x;          // 0..2047; 64 blocks per batch
  const int bb = blk >> 6;
  __shared__ float flagS;
  if (tid < 64) {
    float o0 = ws[bb * 128 + tid] + ws[bb * 128 + 64 + tid];
    float o1 = ws[NSEQ + bb * 128 + tid] + ws[NSEQ + bb * 128 + 64 + tid];
#pragma unroll
    for (int off = 32; off >= 1; off >>= 1) {
      o0 += __shfl_xor(o0, off, 64);
      o1 += __shfl_xor(o1, off, 64);
    }
    if (tid == 0) flagS = (o0 > o1) ? 1.0f : 0.0f;   // swap iff mean0 > mean1
  }
  __syncthreads();
  const bool sw = flagS > 0.5f;
  float4* o4 = (float4*)out;
  const int i = blk * 256 + tid;       // float4 index within trend field
  o4[i] = (float4){0.0f, 0.0f, 0.0f, 0.0f};
  if (sw) {
    float4 p = o4[FIELD / 4 + i];
    float4 r = o4[2 * FIELD / 4 + i];
    o4[FIELD / 4 + i] = r;
    o4[2 * FIELD / 4 + i] = p;
  }
}

extern "C" void kernel_launch(void* const* d_in, const int* in_sizes, int n_in,
                              void* d_out, int out_size, void* d_ws, size_t ws_size,
                              hipStream_t stream) {
  (void)in_sizes; (void)n_in; (void)ws_size; (void)out_size;
  const float* x = (const float*)d_in[0];
  float* out = (float*)d_out;
  float* ws = (float*)d_ws;
  vmd_kernel<<<NSEQ / 4, 512, 0, stream>>>(x, out, ws);
  epi_kernel<<<FIELD / 1024, 256, 0, stream>>>(out, ws);
}